// Round 5
// baseline (70.212 us; speedup 1.0000x reference)
//
#include <hip/hip_runtime.h>

// RBF interpolation via MFMA: D[m][ch] = sum_n w(m,n) * Y[n][ch]
// Y[n][0] = 1 (density), Y[n][1..8] = y_c[n], ch 9..15 = 0.
// w = exp2(e'), e' = an + bn + ax*xx + ay*xy
//   an = -s^2*|g|^2, bn = -s^2*|x|^2, ax = 2s^2*gx, ay = 2s^2*gy,
//   s^2 = 0.5*log2(e)/sigma^2.

typedef float  f32x4 __attribute__((ext_vector_type(4)));
typedef __fp16 half8  __attribute__((ext_vector_type(8)));
typedef __fp16 half2t __attribute__((ext_vector_type(2)));

constexpr int B_  = 8;
constexpr int NC  = 2048;
constexpr int M_  = 128 * 128;
constexpr int NT  = 512;            // n-tile staged in LDS
constexpr int NTP = 520;            // padded f16 row
constexpr int BLK = 256;            // 4 waves
constexpr int WM  = 4;              // m-tiles (of 16) per wave
constexpr int NSPLIT = 2;           // n-split (2 atomic adds: bitwise deterministic)
constexpr int TILES_PER_BLOCK = 4 * WM;                 // 16 tiles = 256 m / block
constexpr int MBLOCKS = M_ / (TILES_PER_BLOCK * 16);    // 64
constexpr int NC_PER_SPLIT = NC / NSPLIT;               // 1024
// grid = B_ * MBLOCKS * NSPLIT = 1024 blocks

__global__ __launch_bounds__(BLK) void rbf_mfma(
    const float* __restrict__ x_c,
    const float* __restrict__ y_c,
    const float* __restrict__ gp,
    const float* __restrict__ sigma_p,
    float* __restrict__ out)
{
    __shared__ __align__(16) float sxx[NT];
    __shared__ __align__(16) float sxy[NT];
    __shared__ __align__(16) float sbn[NT];
    __shared__ __align__(16) __fp16 sy[16 * NTP];   // [ch][n] f16

    const int tid  = (int)threadIdx.x;
    const int lane = tid & 63;
    const int w    = tid >> 6;        // wave id 0..3
    const int q    = lane >> 4;       // quarter 0..3
    const int ch   = lane & 15;       // A-row / B-col

    const int bid   = blockIdx.x;
    const int b     = bid / (MBLOCKS * NSPLIT);
    const int r     = bid % (MBLOCKS * NSPLIT);
    const int split = r / MBLOCKS;
    const int mb    = r % MBLOCKS;
    const int m_base = mb * (TILES_PER_BLOCK * 16);

    const float sigma = sigma_p[0];
    const float s2 = 0.72134752044448170f / (sigma * sigma);
    const float s2x2 = 2.0f * s2;

    // constant B rows: ch 0 = 1.0 (density), ch 9..15 = 0
    for (int i = tid; i < NTP; i += BLK) sy[i] = (__fp16)1.0f;
    for (int rr = 9; rr < 16; ++rr)
        for (int i = tid; i < NTP; i += BLK) sy[rr * NTP + i] = (__fp16)0.0f;

    // per-wave, per-tile A-row constants (row = ch)
    float ax[WM], ay[WM], an[WM];
#pragma unroll
    for (int i = 0; i < WM; ++i) {
        const int mg = m_base + (w * WM + i) * 16 + ch;
        const float2 g = ((const float2*)gp)[mg];
        ax[i] = s2x2 * g.x;
        ay[i] = s2x2 * g.y;
        an[i] = -s2 * (g.x * g.x + g.y * g.y);
    }

    f32x4 acc[WM];
#pragma unroll
    for (int i = 0; i < WM; ++i) acc[i] = (f32x4)0.0f;

    const float2* xb = (const float2*)x_c + (size_t)b * NC;
    const float2* yb = (const float2*)y_c + (size_t)b * NC * 4;
    const int n0 = split * NC_PER_SPLIT;

    for (int t0 = n0; t0 < n0 + NC_PER_SPLIT; t0 += NT) {
        __syncthreads();
        // stage x (SoA) + bn
        for (int i = tid; i < NT; i += BLK) {
            const float2 v = xb[t0 + i];
            sxx[i] = v.x;
            sxy[i] = v.y;
            sbn[i] = -s2 * (v.x * v.x + v.y * v.y);
        }
        // stage y as f16 [ch][n]; y channel j -> B row j+1
        for (int i = tid; i < NT * 4; i += BLK) {
            const int n = i >> 2, c = i & 3;
            const float2 v = yb[(size_t)(t0 + n) * 4 + c];
            const half2t h = __builtin_amdgcn_cvt_pkrtz(v.x, v.y);
            sy[(2 * c + 1) * NTP + n] = h.x;
            sy[(2 * c + 2) * NTP + n] = h.y;
        }
        __syncthreads();

        const __fp16* brow = sy + ch * NTP;

#pragma unroll 2
        for (int ks = 0; ks < NT; ks += 32) {
            const int kq = ks + q * 8;   // this lane's 8 k's
            const f32x4 xxa = *(const f32x4*)(sxx + kq);
            const f32x4 xxb = *(const f32x4*)(sxx + kq + 4);
            const f32x4 xya = *(const f32x4*)(sxy + kq);
            const f32x4 xyb = *(const f32x4*)(sxy + kq + 4);
            const f32x4 bna = *(const f32x4*)(sbn + kq);
            const f32x4 bnb = *(const f32x4*)(sbn + kq + 4);
            const half8 bfrag = *(const half8*)(brow + kq);

#pragma unroll
            for (int i = 0; i < WM; ++i) {
                const float e0 = __builtin_fmaf(ax[i], xxa.x, __builtin_fmaf(ay[i], xya.x, an[i] + bna.x));
                const float e1 = __builtin_fmaf(ax[i], xxa.y, __builtin_fmaf(ay[i], xya.y, an[i] + bna.y));
                const float e2 = __builtin_fmaf(ax[i], xxa.z, __builtin_fmaf(ay[i], xya.z, an[i] + bna.z));
                const float e3 = __builtin_fmaf(ax[i], xxa.w, __builtin_fmaf(ay[i], xya.w, an[i] + bna.w));
                const float e4 = __builtin_fmaf(ax[i], xxb.x, __builtin_fmaf(ay[i], xyb.x, an[i] + bnb.x));
                const float e5 = __builtin_fmaf(ax[i], xxb.y, __builtin_fmaf(ay[i], xyb.y, an[i] + bnb.y));
                const float e6 = __builtin_fmaf(ax[i], xxb.z, __builtin_fmaf(ay[i], xyb.z, an[i] + bnb.z));
                const float e7 = __builtin_fmaf(ax[i], xxb.w, __builtin_fmaf(ay[i], xyb.w, an[i] + bnb.w));
                const half2t w0 = __builtin_amdgcn_cvt_pkrtz(
                    __builtin_amdgcn_exp2f(e0), __builtin_amdgcn_exp2f(e1));
                const half2t w1 = __builtin_amdgcn_cvt_pkrtz(
                    __builtin_amdgcn_exp2f(e2), __builtin_amdgcn_exp2f(e3));
                const half2t w2 = __builtin_amdgcn_cvt_pkrtz(
                    __builtin_amdgcn_exp2f(e4), __builtin_amdgcn_exp2f(e5));
                const half2t w3 = __builtin_amdgcn_cvt_pkrtz(
                    __builtin_amdgcn_exp2f(e6), __builtin_amdgcn_exp2f(e7));
                const half8 afrag = (half8){w0.x, w0.y, w1.x, w1.y,
                                            w2.x, w2.y, w3.x, w3.y};
                acc[i] = __builtin_amdgcn_mfma_f32_16x16x32_f16(afrag, bfrag, acc[i], 0, 0, 0);
            }
        }
    }

    // epilogue: lane holds D rows q*4+0..3, col ch. Atomic-accumulate raw sums.
    float* ob = out + (size_t)b * 9 * M_;
#pragma unroll
    for (int i = 0; i < WM; ++i) {
        if (ch < 9) {
            const int mg = m_base + (w * WM + i) * 16 + q * 4;
            const f32x4 a = acc[i];
            float* p = ob + (size_t)ch * M_ + mg;
            atomicAdd(p + 0, a.x);
            atomicAdd(p + 1, a.y);
            atomicAdd(p + 2, a.z);
            atomicAdd(p + 3, a.w);
        }
    }
}

__global__ __launch_bounds__(BLK) void rbf_normalize(float* __restrict__ out)
{
    const int t = blockIdx.x * BLK + (int)threadIdx.x;   // B*M threads
    const int b = t / M_;
    const int m = t % M_;
    float* ob = out + (size_t)b * 9 * M_;
    const float inv = __builtin_amdgcn_rcpf(ob[m] + 1e-5f);
#pragma unroll
    for (int y = 0; y < 8; ++y)
        ob[(size_t)(y + 1) * M_ + m] *= inv;
}

extern "C" void kernel_launch(void* const* d_in, const int* in_sizes, int n_in,
                              void* d_out, int out_size, void* d_ws, size_t ws_size,
                              hipStream_t stream) {
    const float* x_c   = (const float*)d_in[0];
    const float* y_c   = (const float*)d_in[1];
    const float* gp    = (const float*)d_in[2];
    const float* sigma = (const float*)d_in[3];
    float* out = (float*)d_out;

    hipMemsetAsync(out, 0, (size_t)out_size * sizeof(float), stream);

    dim3 block(BLK);
    dim3 grid1(B_ * MBLOCKS * NSPLIT);      // 1024 blocks
    rbf_mfma<<<grid1, block, 0, stream>>>(x_c, y_c, gp, sigma, out);

    dim3 grid2((B_ * M_) / BLK);            // 512 blocks
    rbf_normalize<<<grid2, block, 0, stream>>>(out);
}

// Round 6
// 24.172 us; speedup vs baseline: 2.9047x; 2.9047x over previous
//
#include <hip/hip_runtime.h>

// Separable RBF interpolation. Grid is a 128x128 tensor-product lattice, so
// w(m,n) = wy(my,n) * wx(mx,n), and
//   D[my][mx][ch] = sum_n wy[my][n] * wx[mx][n] * Y[n][ch],  Y[n][0] = 1.
// Per block: one batch, 16 my x 32 mx, all 9 ch; 4 waves split K=2048,
// partials reduced in-block via LDS in fixed order (deterministic).

typedef float  f32x4 __attribute__((ext_vector_type(4)));
typedef __fp16 half8  __attribute__((ext_vector_type(8)));
typedef __fp16 half2t __attribute__((ext_vector_type(2)));

constexpr int B_  = 8;
constexpr int NC  = 2048;
constexpr int M_  = 128 * 128;
constexpr int BLK = 256;          // 4 waves
constexpr int KW  = 512;          // k-range per wave
constexpr int PH  = 4;            // phases per kernel
constexpr int NTW = 128;          // k per wave-window per phase
constexpr int LDH = NTW + 8;      // padded half stride (136 halfs = 272 B, 16B-aligned)

__global__ __launch_bounds__(BLK) void rbf_sep(
    const float* __restrict__ x_c,
    const float* __restrict__ y_c,
    const float* __restrict__ gp,
    const float* __restrict__ sigma_p,
    float* __restrict__ out)
{
    __shared__ __align__(16) __fp16 swy[4 * 16 * LDH];   // [w][my16][k]
    __shared__ __align__(16) __fp16 swx[4 * 32 * LDH];   // [w][mx32][k]
    __shared__ __align__(16) __fp16 sys[4 * 8 * LDH];    // [w][ch8][k]
    __shared__ __align__(16) float  sxt[4 * NTW];        // s*x.x per window
    __shared__ __align__(16) float  syt[4 * NTW];        // s*x.y per window
    __shared__ float sg[48];                             // s*gy[16], s*gx[32]
    __shared__ float rbuf[2 * 18 * 260];                 // reduce buffer (37.4 KB)

    const int tid  = (int)threadIdx.x;
    const int lane = tid & 63;
    const int w    = tid >> 6;       // wave 0..3
    const int q    = lane >> 4;      // quarter
    const int cl   = lane & 15;      // MFMA row/col lane index

    const int bid = blockIdx.x;
    const int b   = bid >> 5;                 // 32 blocks per batch
    const int myg = (bid >> 2) & 7;
    const int mxg = bid & 3;
    const int my0 = myg * 16;
    const int mx0 = mxg * 32;

    const float sigma = sigma_p[0];
    const float s = __builtin_sqrtf(0.72134752044448170f) / sigma;  // sqrt(0.5*log2e)/sigma

    // scaled grid coords: gy[iy] = gp[iy*256+1], gx[ix] = gp[ix*2]
    if (tid < 16)      sg[tid] = s * gp[(my0 + tid) * 256 + 1];
    else if (tid < 48) sg[tid] = s * gp[(mx0 + (tid - 16)) * 2];

    f32x4 acc[2][9];
#pragma unroll
    for (int t = 0; t < 2; ++t)
#pragma unroll
        for (int c = 0; c < 9; ++c) acc[t][c] = (f32x4)0.0f;

    const float2* xb = (const float2*)x_c + (size_t)b * NC;
    const float4* yb = (const float4*)y_c + (size_t)b * NC * 2;

    for (int p = 0; p < PH; ++p) {
        __syncthreads();   // WAR vs previous compute (and sg ready on p=0)

        // (a) stage x (scaled, SoA) and y (f16 [ch][k]) for all 4 wave-windows
        for (int it = tid; it < 4 * NTW; it += BLK) {
            const int ww = it >> 7, j = it & 127;
            const int k  = ww * KW + p * NTW + j;
            const float2 v = xb[k];
            sxt[it] = s * v.x;
            syt[it] = s * v.y;
            const float4 y0 = yb[(size_t)k * 2];
            const float4 y1 = yb[(size_t)k * 2 + 1];
            __fp16* ysw = sys + ww * (8 * LDH) + j;
            ysw[0 * LDH] = (__fp16)y0.x;
            ysw[1 * LDH] = (__fp16)y0.y;
            ysw[2 * LDH] = (__fp16)y0.z;
            ysw[3 * LDH] = (__fp16)y0.w;
            ysw[4 * LDH] = (__fp16)y1.x;
            ysw[5 * LDH] = (__fp16)y1.y;
            ysw[6 * LDH] = (__fp16)y1.z;
            ysw[7 * LDH] = (__fp16)y1.w;
        }
        __syncthreads();   // sxt/syt ready

        // (b) fill wy: 4w x 16my x 16 j8-groups = 1024 vec-items
        for (int it = tid; it < 1024; it += BLK) {
            const int ww = it >> 8, r = it & 255;
            const int i = r >> 4, j8 = (r & 15) * 8;
            const float sgi = sg[i];
            const f32x4 a0 = *(const f32x4*)(syt + ww * NTW + j8);
            const f32x4 a1 = *(const f32x4*)(syt + ww * NTW + j8 + 4);
            const f32x4 e0 = a0 - sgi, e1 = a1 - sgi;
            const f32x4 m0 = e0 * e0, m1 = e1 * e1;
            const half2t h0 = __builtin_amdgcn_cvt_pkrtz(
                __builtin_amdgcn_exp2f(-m0.x), __builtin_amdgcn_exp2f(-m0.y));
            const half2t h1 = __builtin_amdgcn_cvt_pkrtz(
                __builtin_amdgcn_exp2f(-m0.z), __builtin_amdgcn_exp2f(-m0.w));
            const half2t h2 = __builtin_amdgcn_cvt_pkrtz(
                __builtin_amdgcn_exp2f(-m1.x), __builtin_amdgcn_exp2f(-m1.y));
            const half2t h3 = __builtin_amdgcn_cvt_pkrtz(
                __builtin_amdgcn_exp2f(-m1.z), __builtin_amdgcn_exp2f(-m1.w));
            const half8 hv = (half8){h0.x, h0.y, h1.x, h1.y, h2.x, h2.y, h3.x, h3.y};
            *(half8*)(swy + ww * (16 * LDH) + i * LDH + j8) = hv;
        }
        // (c) fill wx: 4w x 32mx x 16 = 2048 vec-items
        for (int it = tid; it < 2048; it += BLK) {
            const int ww = it >> 9, r = it & 511;
            const int i = r >> 4, j8 = (r & 15) * 8;
            const float sgi = sg[16 + i];
            const f32x4 a0 = *(const f32x4*)(sxt + ww * NTW + j8);
            const f32x4 a1 = *(const f32x4*)(sxt + ww * NTW + j8 + 4);
            const f32x4 e0 = a0 - sgi, e1 = a1 - sgi;
            const f32x4 m0 = e0 * e0, m1 = e1 * e1;
            const half2t h0 = __builtin_amdgcn_cvt_pkrtz(
                __builtin_amdgcn_exp2f(-m0.x), __builtin_amdgcn_exp2f(-m0.y));
            const half2t h1 = __builtin_amdgcn_cvt_pkrtz(
                __builtin_amdgcn_exp2f(-m0.z), __builtin_amdgcn_exp2f(-m0.w));
            const half2t h2 = __builtin_amdgcn_cvt_pkrtz(
                __builtin_amdgcn_exp2f(-m1.x), __builtin_amdgcn_exp2f(-m1.y));
            const half2t h3 = __builtin_amdgcn_cvt_pkrtz(
                __builtin_amdgcn_exp2f(-m1.z), __builtin_amdgcn_exp2f(-m1.w));
            const half8 hv = (half8){h0.x, h0.y, h1.x, h1.y, h2.x, h2.y, h3.x, h3.y};
            *(half8*)(swx + ww * (32 * LDH) + i * LDH + j8) = hv;
        }
        __syncthreads();   // tiles ready

        // (d) compute: 4 k-steps of 32 over this wave's window
        const __fp16* wyb  = swy + w * (16 * LDH) + cl * LDH;
        const __fp16* wxb0 = swx + w * (32 * LDH) + cl * LDH;
        const __fp16* wxb1 = wxb0 + 16 * LDH;
        const __fp16* ysb  = sys + w * (8 * LDH);
#pragma unroll 1
        for (int ks = 0; ks < 4; ++ks) {
            const int kq = ks * 32 + q * 8;
            const half8 af  = *(const half8*)(wyb + kq);
            const half8 bx0 = *(const half8*)(wxb0 + kq);
            const half8 bx1 = *(const half8*)(wxb1 + kq);
            acc[0][0] = __builtin_amdgcn_mfma_f32_16x16x32_f16(af, bx0, acc[0][0], 0, 0, 0);
            acc[1][0] = __builtin_amdgcn_mfma_f32_16x16x32_f16(af, bx1, acc[1][0], 0, 0, 0);
#pragma unroll
            for (int c = 0; c < 8; ++c) {
                const half8 yf = *(const half8*)(ysb + c * LDH + kq);
                acc[0][c + 1] = __builtin_amdgcn_mfma_f32_16x16x32_f16(af, bx0 * yf, acc[0][c + 1], 0, 0, 0);
                acc[1][c + 1] = __builtin_amdgcn_mfma_f32_16x16x32_f16(af, bx1 * yf, acc[1][c + 1], 0, 0, 0);
            }
        }
    }

    // ---- in-block K-reduction: final = (w0 + w1) + (w2 + w3), fixed order ----
    __syncthreads();
    if (w == 1 || w == 3) {
        float* rb = rbuf + (w >> 1) * (18 * 260);
#pragma unroll
        for (int t = 0; t < 2; ++t)
#pragma unroll
            for (int c = 0; c < 9; ++c) {
                const int td = t * 9 + c;
#pragma unroll
                for (int r = 0; r < 4; ++r)
                    rb[td * 260 + (q * 4 + r) * 16 + cl] = acc[t][c][r];
            }
    }
    __syncthreads();
    if (w == 0 || w == 2) {
        const float* rb = rbuf + (w >> 1) * (18 * 260);
#pragma unroll
        for (int t = 0; t < 2; ++t)
#pragma unroll
            for (int c = 0; c < 9; ++c) {
                const int td = t * 9 + c;
#pragma unroll
                for (int r = 0; r < 4; ++r)
                    acc[t][c][r] += rb[td * 260 + (q * 4 + r) * 16 + cl];
            }
        if (w == 2) {
            float* rb2 = rbuf + 1 * (18 * 260);
#pragma unroll
            for (int t = 0; t < 2; ++t)
#pragma unroll
                for (int c = 0; c < 9; ++c) {
                    const int td = t * 9 + c;
#pragma unroll
                    for (int r = 0; r < 4; ++r)
                        rb2[td * 260 + (q * 4 + r) * 16 + cl] = acc[t][c][r];
                }
        }
    }
    __syncthreads();
    if (w == 0) {
        const float* rb = rbuf + 1 * (18 * 260);
        float* ob = out + (size_t)b * 9 * M_;
#pragma unroll
        for (int t = 0; t < 2; ++t) {
#pragma unroll
            for (int c = 0; c < 9; ++c) {
                const int td = t * 9 + c;
#pragma unroll
                for (int r = 0; r < 4; ++r)
                    acc[t][c][r] += rb[td * 260 + (q * 4 + r) * 16 + cl];
            }
            // D-fragment: row = q*4 + r (my), col = cl (mx)
            f32x4 inv;
#pragma unroll
            for (int r = 0; r < 4; ++r)
                inv[r] = __builtin_amdgcn_rcpf(acc[t][0][r] + 1e-5f);
#pragma unroll
            for (int r = 0; r < 4; ++r) {
                const int m = (my0 + q * 4 + r) * 128 + mx0 + t * 16 + cl;
                ob[m] = acc[t][0][r];                        // density (ch 0)
#pragma unroll
                for (int c = 1; c < 9; ++c)
                    ob[(size_t)c * M_ + m] = acc[t][c][r] * inv[r];
            }
        }
    }
}

extern "C" void kernel_launch(void* const* d_in, const int* in_sizes, int n_in,
                              void* d_out, int out_size, void* d_ws, size_t ws_size,
                              hipStream_t stream) {
    const float* x_c   = (const float*)d_in[0];
    const float* y_c   = (const float*)d_in[1];
    const float* gp    = (const float*)d_in[2];
    const float* sigma = (const float*)d_in[3];
    float* out = (float*)d_out;

    dim3 grid(B_ * 32);      // 256 blocks: 8 batches x 8 my-groups x 4 mx-groups
    dim3 block(BLK);
    rbf_sep<<<grid, block, 0, stream>>>(x_c, y_c, gp, sigma, out);
}

// Round 7
// 23.609 us; speedup vs baseline: 2.9739x; 1.0239x over previous
//
#include <hip/hip_runtime.h>

// Separable RBF interpolation. Grid is a 128x128 tensor-product lattice:
// w(m,n) = wy(my,n) * wx(mx,n);  D[my][mx][ch] = sum_n wy*wx*Y[n][ch], Y[n][0]=1.
// Block = (batch, 16 my, 16 mx), 4 waves split K=2048 (512 each, 4 phases of 128).
// In-block LDS tree-reduce in fixed order (deterministic), cooperative store.

typedef float  f32x4 __attribute__((ext_vector_type(4)));
typedef __fp16 half8  __attribute__((ext_vector_type(8)));
typedef __fp16 half2t __attribute__((ext_vector_type(2)));

constexpr int B_  = 8;
constexpr int NC  = 2048;
constexpr int M_  = 128 * 128;
constexpr int BLK = 256;          // 4 waves
constexpr int KW  = 512;          // k-range per wave
constexpr int PH  = 4;            // phases
constexpr int NTW = 128;          // k per wave-window per phase
constexpr int LDH = NTW + 8;      // padded half stride (136)

// LDS pool carve (bytes)
constexpr int OFF_SWY = 0;                       // 4*16*LDH halfs = 17408 B
constexpr int OFF_SWX = OFF_SWY + 4 * 16 * LDH * 2;   // 17408
constexpr int OFF_SYS = OFF_SWX + 4 * 16 * LDH * 2;   // 34816 (+8704)
constexpr int OFF_SXT = OFF_SYS + 4 * 8 * LDH * 2;    // 43520 (+2048)
constexpr int OFF_SYT = OFF_SXT + 4 * NTW * 4;        // 45568 (+2048)
constexpr int OFF_SG  = OFF_SYT + 4 * NTW * 4;        // 47616 (+128)
constexpr int POOL_B  = OFF_SG + 32 * 4;              // 47744 B -> 2+ blocks/CU
// epilogue aliases (used only after a barrier, tiles dead):
constexpr int RSLOT_F = 9 * 260;                 // floats per reduce slot (9360 B)
constexpr int OFF_RB2 = OFF_SYS;                 // 9*16*16 f32 = 9216 B over sys/sxt

__global__ __launch_bounds__(BLK) void rbf_sep(
    const float* __restrict__ x_c,
    const float* __restrict__ y_c,
    const float* __restrict__ gp,
    const float* __restrict__ sigma_p,
    float* __restrict__ out)
{
    __shared__ __align__(16) char pool[POOL_B];
    __fp16* swy = (__fp16*)(pool + OFF_SWY);   // [w][my16][k]
    __fp16* swx = (__fp16*)(pool + OFF_SWX);   // [w][mx16][k]
    __fp16* sys = (__fp16*)(pool + OFF_SYS);   // [w][ch8][k]
    float*  sxt = (float*)(pool + OFF_SXT);    // s*x.x
    float*  syt = (float*)(pool + OFF_SYT);    // s*x.y
    float*  sg  = (float*)(pool + OFF_SG);     // s*gy[16], s*gx[16]

    const int tid  = (int)threadIdx.x;
    const int lane = tid & 63;
    const int w    = tid >> 6;
    const int q    = lane >> 4;
    const int cl   = lane & 15;

    const int bid = blockIdx.x;
    const int b   = bid >> 6;                 // 64 blocks per batch
    const int myg = (bid >> 3) & 7;
    const int mxg = bid & 7;
    const int my0 = myg * 16;
    const int mx0 = mxg * 16;

    const float sigma = sigma_p[0];
    const float s = __builtin_sqrtf(0.72134752044448170f) / sigma;

    if (tid < 16)      sg[tid] = s * gp[(my0 + tid) * 256 + 1];
    else if (tid < 32) sg[tid] = s * gp[(mx0 + (tid - 16)) * 2];

    f32x4 acc[9];
#pragma unroll
    for (int c = 0; c < 9; ++c) acc[c] = (f32x4)0.0f;

    const float2* xb = (const float2*)x_c + (size_t)b * NC;
    const float4* yb = (const float4*)y_c + (size_t)b * NC * 2;

    for (int p = 0; p < PH; ++p) {
        __syncthreads();   // WAR vs previous compute (sg ready on p=0)

        // (a) stage x (scaled SoA) + y (f16 [ch][k]) for all 4 wave-windows
        for (int it = tid; it < 4 * NTW; it += BLK) {
            const int ww = it >> 7, j = it & 127;
            const int k  = ww * KW + p * NTW + j;
            const float2 v = xb[k];
            sxt[it] = s * v.x;
            syt[it] = s * v.y;
            const float4 y0 = yb[(size_t)k * 2];
            const float4 y1 = yb[(size_t)k * 2 + 1];
            __fp16* ysw = sys + ww * (8 * LDH) + j;
            ysw[0 * LDH] = (__fp16)y0.x;
            ysw[1 * LDH] = (__fp16)y0.y;
            ysw[2 * LDH] = (__fp16)y0.z;
            ysw[3 * LDH] = (__fp16)y0.w;
            ysw[4 * LDH] = (__fp16)y1.x;
            ysw[5 * LDH] = (__fp16)y1.y;
            ysw[6 * LDH] = (__fp16)y1.z;
            ysw[7 * LDH] = (__fp16)y1.w;
        }
        __syncthreads();   // sxt/syt ready

        // (b) fill wy: 4w x 16my x 16 groups; (c) fill wx: same shape
        for (int it = tid; it < 2048; it += BLK) {
            const bool isx = it >= 1024;
            const int r3 = it & 1023;
            const int ww = r3 >> 8, r = r3 & 255;
            const int i = r >> 4, j8 = (r & 15) * 8;
            const float sgi = sg[(isx ? 16 : 0) + i];
            const float* src = (isx ? sxt : syt) + ww * NTW + j8;
            const f32x4 a0 = *(const f32x4*)(src);
            const f32x4 a1 = *(const f32x4*)(src + 4);
            const f32x4 e0 = a0 - sgi, e1 = a1 - sgi;
            const f32x4 m0 = e0 * e0, m1 = e1 * e1;
            const half2t h0 = __builtin_amdgcn_cvt_pkrtz(
                __builtin_amdgcn_exp2f(-m0.x), __builtin_amdgcn_exp2f(-m0.y));
            const half2t h1 = __builtin_amdgcn_cvt_pkrtz(
                __builtin_amdgcn_exp2f(-m0.z), __builtin_amdgcn_exp2f(-m0.w));
            const half2t h2 = __builtin_amdgcn_cvt_pkrtz(
                __builtin_amdgcn_exp2f(-m1.x), __builtin_amdgcn_exp2f(-m1.y));
            const half2t h3 = __builtin_amdgcn_cvt_pkrtz(
                __builtin_amdgcn_exp2f(-m1.z), __builtin_amdgcn_exp2f(-m1.w));
            const half8 hv = (half8){h0.x, h0.y, h1.x, h1.y, h2.x, h2.y, h3.x, h3.y};
            __fp16* dst = (isx ? swx : swy) + ww * (16 * LDH) + i * LDH + j8;
            *(half8*)dst = hv;
        }
        __syncthreads();   // tiles ready

        // (d) compute: 4 k-steps of 32 over this wave's window
        const __fp16* wyb = swy + w * (16 * LDH) + cl * LDH;
        const __fp16* wxb = swx + w * (16 * LDH) + cl * LDH;
        const __fp16* ysb = sys + w * (8 * LDH);
#pragma unroll 1
        for (int ks = 0; ks < 4; ++ks) {
            const int kq = ks * 32 + q * 8;
            const half8 af = *(const half8*)(wyb + kq);
            const half8 bx = *(const half8*)(wxb + kq);
            acc[0] = __builtin_amdgcn_mfma_f32_16x16x32_f16(af, bx, acc[0], 0, 0, 0);
#pragma unroll
            for (int c = 0; c < 8; ++c) {
                const half8 yf = *(const half8*)(ysb + c * LDH + kq);
                acc[c + 1] = __builtin_amdgcn_mfma_f32_16x16x32_f16(af, bx * yf, acc[c + 1], 0, 0, 0);
            }
        }
    }

    // ---- in-block K-reduce: final = (w0 + w1) + (w2 + w3), fixed order ----
    __syncthreads();                       // tiles dead; alias reduce bufs
    float* rslot = (float*)(pool);         // 2 slots of RSLOT_F floats
    if (w == 1 || w == 3) {
        float* rb = rslot + (w >> 1) * RSLOT_F;
#pragma unroll
        for (int c = 0; c < 9; ++c)
#pragma unroll
            for (int r = 0; r < 4; ++r)
                rb[c * 260 + (q * 4 + r) * 16 + cl] = acc[c][r];
    }
    __syncthreads();
    if (w == 0 || w == 2) {
        const float* rb = rslot + (w >> 1) * RSLOT_F;
#pragma unroll
        for (int c = 0; c < 9; ++c)
#pragma unroll
            for (int r = 0; r < 4; ++r)
                acc[c][r] += rb[c * 260 + (q * 4 + r) * 16 + cl];
        if (w == 2) {
            float* rb2 = rslot + 1 * RSLOT_F;
#pragma unroll
            for (int c = 0; c < 9; ++c)
#pragma unroll
                for (int r = 0; r < 4; ++r)
                    rb2[c * 260 + (q * 4 + r) * 16 + cl] = acc[c][r];
        }
    }
    __syncthreads();
    float* rb2 = (float*)(pool + OFF_RB2);   // [ch][my16][mx16] final tile
    if (w == 0) {
        const float* rb = rslot + 1 * RSLOT_F;
#pragma unroll
        for (int c = 0; c < 9; ++c)
#pragma unroll
            for (int r = 0; r < 4; ++r)
                acc[c][r] += rb[c * 260 + (q * 4 + r) * 16 + cl];
        f32x4 inv;
#pragma unroll
        for (int r = 0; r < 4; ++r)
            inv[r] = __builtin_amdgcn_rcpf(acc[0][r] + 1e-5f);
#pragma unroll
        for (int c = 0; c < 9; ++c)
#pragma unroll
            for (int r = 0; r < 4; ++r)
                rb2[c * 256 + (q * 4 + r) * 16 + cl] =
                    (c == 0) ? acc[0][r] : acc[c][r] * inv[r];
    }
    __syncthreads();

    // cooperative coalesced store: 9ch x 16my x 4 quads = 576 f32x4
    float* ob = out + (size_t)b * 9 * M_;
    for (int it = tid; it < 576; it += BLK) {
        const int c  = it >> 6;
        const int my = (it & 63) >> 2;
        const int xq = it & 3;
        const f32x4 v = *(const f32x4*)(rb2 + c * 256 + my * 16 + xq * 4);
        *(f32x4*)(ob + (size_t)c * M_ + (my0 + my) * 128 + mx0 + xq * 4) = v;
    }
}

extern "C" void kernel_launch(void* const* d_in, const int* in_sizes, int n_in,
                              void* d_out, int out_size, void* d_ws, size_t ws_size,
                              hipStream_t stream) {
    const float* x_c   = (const float*)d_in[0];
    const float* y_c   = (const float*)d_in[1];
    const float* gp    = (const float*)d_in[2];
    const float* sigma = (const float*)d_in[3];
    float* out = (float*)d_out;

    dim3 grid(B_ * 64);      // 512 blocks: 8 batches x 8 my-groups x 8 mx-groups
    dim3 block(BLK);
    rbf_sep<<<grid, block, 0, stream>>>(x_c, y_c, gp, sigma, out);
}

// Round 8
// 20.815 us; speedup vs baseline: 3.3732x; 1.1342x over previous
//
#include <hip/hip_runtime.h>

// Separable RBF interpolation. Grid is a 128x128 tensor-product lattice:
// w(m,n) = wy(my,n) * wx(mx,n);  D[my][mx][ch] = sum_n wy*wx*Y[n][ch], Y[n][0]=1.
// Block = (batch, 16 my, 16 mx); 4 waves split K=2048 (512 each).
// wy/wx MFMA fragments are computed IN REGISTERS (2 broadcast LDS reads + 8 exp2
// per fragment) — no tile fill, no phases. x/y staged to LDS once.
// In-block LDS tree-reduce in fixed order (deterministic), cooperative store.

typedef float  f32x4 __attribute__((ext_vector_type(4)));
typedef __fp16 half8  __attribute__((ext_vector_type(8)));
typedef __fp16 half2t __attribute__((ext_vector_type(2)));

constexpr int B_  = 8;
constexpr int NC  = 2048;
constexpr int M_  = 128 * 128;
constexpr int BLK = 256;          // 4 waves
constexpr int KW  = 512;          // k-range per wave
constexpr int LDHY = NC + 8;      // padded f16 row stride for y (2056)

// LDS pool carve (bytes)
constexpr int OFF_SXT = 0;                         // 2048 f32 = 8192 B (s*x.x)
constexpr int OFF_SYT = OFF_SXT + NC * 4;          // 8192  (+8192)  (s*x.y)
constexpr int OFF_SYS = OFF_SYT + NC * 4;          // 16384 (+32896) y f16 [8][LDHY]
constexpr int OFF_SG  = OFF_SYS + 8 * LDHY * 2;    // 49280 (+128)
constexpr int POOL_B  = OFF_SG + 32 * 4;           // 49408 B -> 2+ blocks/CU
// epilogue aliases (tiles dead after compute, separated by barriers):
constexpr int RSLOT_F = 9 * 260;                   // floats per reduce slot (9360 B)
constexpr int OFF_RB2 = 20480;                     // [9][16][16] f32 = 9216 B

__global__ __launch_bounds__(BLK) void rbf_sep(
    const float* __restrict__ x_c,
    const float* __restrict__ y_c,
    const float* __restrict__ gp,
    const float* __restrict__ sigma_p,
    float* __restrict__ out)
{
    __shared__ __align__(16) char pool[POOL_B];
    float*  sxt = (float*)(pool + OFF_SXT);
    float*  syt = (float*)(pool + OFF_SYT);
    __fp16* sys = (__fp16*)(pool + OFF_SYS);
    float*  sg  = (float*)(pool + OFF_SG);

    const int tid  = (int)threadIdx.x;
    const int lane = tid & 63;
    const int w    = tid >> 6;
    const int q    = lane >> 4;
    const int cl   = lane & 15;

    const int bid = blockIdx.x;
    const int b   = bid >> 6;                 // 64 blocks per batch
    const int myg = (bid >> 3) & 7;
    const int mxg = bid & 7;
    const int my0 = myg * 16;
    const int mx0 = mxg * 16;

    const float sigma = sigma_p[0];
    const float s = __builtin_sqrtf(0.72134752044448170f) / sigma;

    if (tid < 16)      sg[tid] = s * gp[(my0 + tid) * 256 + 1];
    else if (tid < 32) sg[tid] = s * gp[(mx0 + (tid - 16)) * 2];

    // stage x (scaled SoA f32) and y (f16 [ch][k]) for the full K range
    const float2* xb = (const float2*)x_c + (size_t)b * NC;
    const float4* yb = (const float4*)y_c + (size_t)b * NC * 2;
    for (int it = tid; it < NC; it += BLK) {
        const float2 v = xb[it];
        sxt[it] = s * v.x;
        syt[it] = s * v.y;
        const float4 y0 = yb[(size_t)it * 2];
        const float4 y1 = yb[(size_t)it * 2 + 1];
        __fp16* yw = sys + it;
        yw[0 * LDHY] = (__fp16)y0.x;
        yw[1 * LDHY] = (__fp16)y0.y;
        yw[2 * LDHY] = (__fp16)y0.z;
        yw[3 * LDHY] = (__fp16)y0.w;
        yw[4 * LDHY] = (__fp16)y1.x;
        yw[5 * LDHY] = (__fp16)y1.y;
        yw[6 * LDHY] = (__fp16)y1.z;
        yw[7 * LDHY] = (__fp16)y1.w;
    }
    __syncthreads();

    const float sgy_r = sg[cl];
    const float sgx_r = sg[16 + cl];

    f32x4 acc[9];
#pragma unroll
    for (int c = 0; c < 9; ++c) acc[c] = (f32x4)0.0f;

    // main loop: each wave covers K window [w*KW, (w+1)*KW), steps of 32
    const int kbase = w * KW;
#pragma unroll 1
    for (int ks = 0; ks < KW / 32; ++ks) {
        const int kq = kbase + ks * 32 + q * 8;

        // A-fragment wy: row=cl, 8 k's (broadcast reads + in-register exp)
        const f32x4 ya0 = *(const f32x4*)(syt + kq);
        const f32x4 ya1 = *(const f32x4*)(syt + kq + 4);
        const f32x4 ye0 = ya0 - sgy_r, ye1 = ya1 - sgy_r;
        const f32x4 ym0 = ye0 * ye0,   ym1 = ye1 * ye1;
        const half2t a0 = __builtin_amdgcn_cvt_pkrtz(
            __builtin_amdgcn_exp2f(-ym0.x), __builtin_amdgcn_exp2f(-ym0.y));
        const half2t a1 = __builtin_amdgcn_cvt_pkrtz(
            __builtin_amdgcn_exp2f(-ym0.z), __builtin_amdgcn_exp2f(-ym0.w));
        const half2t a2 = __builtin_amdgcn_cvt_pkrtz(
            __builtin_amdgcn_exp2f(-ym1.x), __builtin_amdgcn_exp2f(-ym1.y));
        const half2t a3 = __builtin_amdgcn_cvt_pkrtz(
            __builtin_amdgcn_exp2f(-ym1.z), __builtin_amdgcn_exp2f(-ym1.w));
        const half8 af = (half8){a0.x, a0.y, a1.x, a1.y, a2.x, a2.y, a3.x, a3.y};

        // B-fragment wx: col=cl
        const f32x4 xa0 = *(const f32x4*)(sxt + kq);
        const f32x4 xa1 = *(const f32x4*)(sxt + kq + 4);
        const f32x4 xe0 = xa0 - sgx_r, xe1 = xa1 - sgx_r;
        const f32x4 xm0 = xe0 * xe0,   xm1 = xe1 * xe1;
        const half2t b0 = __builtin_amdgcn_cvt_pkrtz(
            __builtin_amdgcn_exp2f(-xm0.x), __builtin_amdgcn_exp2f(-xm0.y));
        const half2t b1 = __builtin_amdgcn_cvt_pkrtz(
            __builtin_amdgcn_exp2f(-xm0.z), __builtin_amdgcn_exp2f(-xm0.w));
        const half2t b2 = __builtin_amdgcn_cvt_pkrtz(
            __builtin_amdgcn_exp2f(-xm1.x), __builtin_amdgcn_exp2f(-xm1.y));
        const half2t b3 = __builtin_amdgcn_cvt_pkrtz(
            __builtin_amdgcn_exp2f(-xm1.z), __builtin_amdgcn_exp2f(-xm1.w));
        const half8 bx = (half8){b0.x, b0.y, b1.x, b1.y, b2.x, b2.y, b3.x, b3.y};

        acc[0] = __builtin_amdgcn_mfma_f32_16x16x32_f16(af, bx, acc[0], 0, 0, 0);
        const __fp16* yp = sys + kq;
#pragma unroll
        for (int c = 0; c < 8; ++c) {
            const half8 yf = *(const half8*)(yp + c * LDHY);
            acc[c + 1] = __builtin_amdgcn_mfma_f32_16x16x32_f16(af, bx * yf, acc[c + 1], 0, 0, 0);
        }
    }

    // ---- in-block K-reduce: final = (w0 + w1) + (w2 + w3), fixed order ----
    __syncthreads();                       // tiles dead; alias reduce bufs
    float* rslot = (float*)(pool);         // 2 slots of RSLOT_F floats
    if (w == 1 || w == 3) {
        float* rb = rslot + (w >> 1) * RSLOT_F;
#pragma unroll
        for (int c = 0; c < 9; ++c)
#pragma unroll
            for (int r = 0; r < 4; ++r)
                rb[c * 260 + (q * 4 + r) * 16 + cl] = acc[c][r];
    }
    __syncthreads();
    if (w == 0 || w == 2) {
        const float* rb = rslot + (w >> 1) * RSLOT_F;
#pragma unroll
        for (int c = 0; c < 9; ++c)
#pragma unroll
            for (int r = 0; r < 4; ++r)
                acc[c][r] += rb[c * 260 + (q * 4 + r) * 16 + cl];
        if (w == 2) {
            float* rb2w = rslot + 1 * RSLOT_F;
#pragma unroll
            for (int c = 0; c < 9; ++c)
#pragma unroll
                for (int r = 0; r < 4; ++r)
                    rb2w[c * 260 + (q * 4 + r) * 16 + cl] = acc[c][r];
        }
    }
    __syncthreads();
    float* rb2 = (float*)(pool + OFF_RB2);   // [ch][my16][mx16] final tile
    if (w == 0) {
        const float* rb = rslot + 1 * RSLOT_F;
#pragma unroll
        for (int c = 0; c < 9; ++c)
#pragma unroll
            for (int r = 0; r < 4; ++r)
                acc[c][r] += rb[c * 260 + (q * 4 + r) * 16 + cl];
        f32x4 inv;
#pragma unroll
        for (int r = 0; r < 4; ++r)
            inv[r] = __builtin_amdgcn_rcpf(acc[0][r] + 1e-5f);
#pragma unroll
        for (int c = 0; c < 9; ++c)
#pragma unroll
            for (int r = 0; r < 4; ++r)
                rb2[c * 256 + (q * 4 + r) * 16 + cl] =
                    (c == 0) ? acc[0][r] : acc[c][r] * inv[r];
    }
    __syncthreads();

    // cooperative coalesced store: 9ch x 16my x 4 quads = 576 f32x4
    float* ob = out + (size_t)b * 9 * M_;
    for (int it = tid; it < 576; it += BLK) {
        const int c  = it >> 6;
        const int my = (it & 63) >> 2;
        const int xq = it & 3;
        const f32x4 v = *(const f32x4*)(rb2 + c * 256 + my * 16 + xq * 4);
        *(f32x4*)(ob + (size_t)c * M_ + (my0 + my) * 128 + mx0 + xq * 4) = v;
    }
}

extern "C" void kernel_launch(void* const* d_in, const int* in_sizes, int n_in,
                              void* d_out, int out_size, void* d_ws, size_t ws_size,
                              hipStream_t stream) {
    const float* x_c   = (const float*)d_in[0];
    const float* y_c   = (const float*)d_in[1];
    const float* gp    = (const float*)d_in[2];
    const float* sigma = (const float*)d_in[3];
    float* out = (float*)d_out;

    dim3 grid(B_ * 64);      // 512 blocks: 8 batches x 8 my-groups x 8 mx-groups
    dim3 block(BLK);
    rbf_sep<<<grid, block, 0, stream>>>(x_c, y_c, gp, sigma, out);
}

// Round 9
// 17.740 us; speedup vs baseline: 3.9578x; 1.1733x over previous
//
#include <hip/hip_runtime.h>

// Separable RBF interpolation. Grid is a 128x128 tensor-product lattice:
// w(m,n) = wy(my,n) * wx(mx,n);  D[my][mx][ch] = sum_n wy*wx*Y[n][ch], Y[n][0]=1.
// Block = (batch, 16 my, 16 mx); 8 waves split K=2048 (256 each).
// wy/wx MFMA fragments computed IN REGISTERS (broadcast LDS reads + 8 exp2 each).
// x/y staged to LDS once. Flat 2-barrier reduce (fixed order), parallel store.

typedef float  f32x4 __attribute__((ext_vector_type(4)));
typedef __fp16 half8  __attribute__((ext_vector_type(8)));
typedef __fp16 half2t __attribute__((ext_vector_type(2)));

constexpr int B_  = 8;
constexpr int NC  = 2048;
constexpr int M_  = 128 * 128;
constexpr int BLK = 512;          // 8 waves
constexpr int KW  = 256;          // k-range per wave
constexpr int LDHY = NC + 8;      // padded f16 row stride for y (2056)

// LDS pool carve (bytes)
constexpr int OFF_SXT = 0;                         // 2048 f32 (s*x.x)
constexpr int OFF_SYT = OFF_SXT + NC * 4;          // 8192  (s*x.y)
constexpr int OFF_SYS = OFF_SYT + NC * 4;          // 16384 y f16 [8][LDHY]
constexpr int OFF_SG  = OFF_SYS + 8 * LDHY * 2;    // 49280
constexpr int POOL_B  = OFF_SG + 32 * 4;           // 49408 B -> 2 blocks/CU
// epilogue alias (tiles dead, barrier-separated): 4 slots of [9][256] f32 = 36864 B
constexpr int SLOT_F = 9 * 256;

__global__ __launch_bounds__(BLK) void rbf_sep(
    const float* __restrict__ x_c,
    const float* __restrict__ y_c,
    const float* __restrict__ gp,
    const float* __restrict__ sigma_p,
    float* __restrict__ out)
{
    __shared__ __align__(16) char pool[POOL_B];
    float*  sxt = (float*)(pool + OFF_SXT);
    float*  syt = (float*)(pool + OFF_SYT);
    __fp16* sys = (__fp16*)(pool + OFF_SYS);
    float*  sg  = (float*)(pool + OFF_SG);

    const int tid  = (int)threadIdx.x;
    const int lane = tid & 63;
    const int w    = tid >> 6;       // wave 0..7
    const int q    = lane >> 4;
    const int cl   = lane & 15;

    const int bid = blockIdx.x;
    const int b   = bid >> 6;                 // 64 blocks per batch
    const int myg = (bid >> 3) & 7;
    const int mxg = bid & 7;
    const int my0 = myg * 16;
    const int mx0 = mxg * 16;

    const float sigma = sigma_p[0];
    const float s = __builtin_sqrtf(0.72134752044448170f) / sigma;

    if (tid < 16)      sg[tid] = s * gp[(my0 + tid) * 256 + 1];
    else if (tid < 32) sg[tid] = s * gp[(mx0 + (tid - 16)) * 2];

    // stage x (scaled SoA f32) and y (f16 [ch][k]) for the full K range
    const float2* xb = (const float2*)x_c + (size_t)b * NC;
    const float4* yb = (const float4*)y_c + (size_t)b * NC * 2;
    for (int it = tid; it < NC; it += BLK) {
        const float2 v = xb[it];
        sxt[it] = s * v.x;
        syt[it] = s * v.y;
        const float4 y0 = yb[(size_t)it * 2];
        const float4 y1 = yb[(size_t)it * 2 + 1];
        __fp16* yw = sys + it;
        yw[0 * LDHY] = (__fp16)y0.x;
        yw[1 * LDHY] = (__fp16)y0.y;
        yw[2 * LDHY] = (__fp16)y0.z;
        yw[3 * LDHY] = (__fp16)y0.w;
        yw[4 * LDHY] = (__fp16)y1.x;
        yw[5 * LDHY] = (__fp16)y1.y;
        yw[6 * LDHY] = (__fp16)y1.z;
        yw[7 * LDHY] = (__fp16)y1.w;
    }
    __syncthreads();

    const float sgy_r = sg[cl];
    const float sgx_r = sg[16 + cl];

    f32x4 acc[9];
#pragma unroll
    for (int c = 0; c < 9; ++c) acc[c] = (f32x4)0.0f;

    // main loop: each wave covers K window [w*KW, (w+1)*KW), steps of 32
    const int kbase = w * KW;
#pragma unroll 2
    for (int ks = 0; ks < KW / 32; ++ks) {
        const int kq = kbase + ks * 32 + q * 8;

        // A-fragment wy: row=cl (broadcast reads + in-register exp)
        const f32x4 ya0 = *(const f32x4*)(syt + kq);
        const f32x4 ya1 = *(const f32x4*)(syt + kq + 4);
        const f32x4 ye0 = ya0 - sgy_r, ye1 = ya1 - sgy_r;
        const f32x4 ym0 = ye0 * ye0,   ym1 = ye1 * ye1;
        const half2t a0 = __builtin_amdgcn_cvt_pkrtz(
            __builtin_amdgcn_exp2f(-ym0.x), __builtin_amdgcn_exp2f(-ym0.y));
        const half2t a1 = __builtin_amdgcn_cvt_pkrtz(
            __builtin_amdgcn_exp2f(-ym0.z), __builtin_amdgcn_exp2f(-ym0.w));
        const half2t a2 = __builtin_amdgcn_cvt_pkrtz(
            __builtin_amdgcn_exp2f(-ym1.x), __builtin_amdgcn_exp2f(-ym1.y));
        const half2t a3 = __builtin_amdgcn_cvt_pkrtz(
            __builtin_amdgcn_exp2f(-ym1.z), __builtin_amdgcn_exp2f(-ym1.w));
        const half8 af = (half8){a0.x, a0.y, a1.x, a1.y, a2.x, a2.y, a3.x, a3.y};

        // B-fragment wx: col=cl
        const f32x4 xa0 = *(const f32x4*)(sxt + kq);
        const f32x4 xa1 = *(const f32x4*)(sxt + kq + 4);
        const f32x4 xe0 = xa0 - sgx_r, xe1 = xa1 - sgx_r;
        const f32x4 xm0 = xe0 * xe0,   xm1 = xe1 * xe1;
        const half2t b0 = __builtin_amdgcn_cvt_pkrtz(
            __builtin_amdgcn_exp2f(-xm0.x), __builtin_amdgcn_exp2f(-xm0.y));
        const half2t b1 = __builtin_amdgcn_cvt_pkrtz(
            __builtin_amdgcn_exp2f(-xm0.z), __builtin_amdgcn_exp2f(-xm0.w));
        const half2t b2 = __builtin_amdgcn_cvt_pkrtz(
            __builtin_amdgcn_exp2f(-xm1.x), __builtin_amdgcn_exp2f(-xm1.y));
        const half2t b3 = __builtin_amdgcn_cvt_pkrtz(
            __builtin_amdgcn_exp2f(-xm1.z), __builtin_amdgcn_exp2f(-xm1.w));
        const half8 bx = (half8){b0.x, b0.y, b1.x, b1.y, b2.x, b2.y, b3.x, b3.y};

        acc[0] = __builtin_amdgcn_mfma_f32_16x16x32_f16(af, bx, acc[0], 0, 0, 0);
        const __fp16* yp = sys + kq;
#pragma unroll
        for (int c = 0; c < 8; ++c) {
            const half8 yf = *(const half8*)(yp + c * LDHY);
            acc[c + 1] = __builtin_amdgcn_mfma_f32_16x16x32_f16(af, bx * yf, acc[c + 1], 0, 0, 0);
        }
    }

    // ---- flat reduce: slot_s = acc_{s+4} + acc_s; final = (s0+s1)+(s2+s3) ----
    __syncthreads();                       // tiles dead; alias slot bufs
    float* slots = (float*)pool;           // [4][9][256]
    if (w >= 4) {
        float* rb = slots + (w - 4) * SLOT_F;
#pragma unroll
        for (int c = 0; c < 9; ++c)
#pragma unroll
            for (int r = 0; r < 4; ++r)
                rb[c * 256 + (q * 4 + r) * 16 + cl] = acc[c][r];
    }
    __syncthreads();
    if (w < 4) {
        float* rb = slots + w * SLOT_F;
#pragma unroll
        for (int c = 0; c < 9; ++c)
#pragma unroll
            for (int r = 0; r < 4; ++r) {
                const int idx = c * 256 + (q * 4 + r) * 16 + cl;
                rb[idx] = rb[idx] + acc[c][r];   // acc_{w+4} + acc_w (fixed order)
            }
    }
    __syncthreads();

    // final 4-way sum + normalize + store, fully parallel over 256 m's
    if (tid < 256) {
        float* ob = out + (size_t)b * 9 * M_;
        const int my = tid >> 4, mx = tid & 15;
        const size_t mo = (size_t)(my0 + my) * 128 + mx0 + mx;
        float v[9];
#pragma unroll
        for (int c = 0; c < 9; ++c) {
            const int idx = c * 256 + tid;
            v[c] = (slots[idx] + slots[SLOT_F + idx]) +
                   (slots[2 * SLOT_F + idx] + slots[3 * SLOT_F + idx]);
        }
        const float inv = __builtin_amdgcn_rcpf(v[0] + 1e-5f);
        ob[mo] = v[0];
#pragma unroll
        for (int c = 1; c < 9; ++c)
            ob[(size_t)c * M_ + mo] = v[c] * inv;
    }
}

extern "C" void kernel_launch(void* const* d_in, const int* in_sizes, int n_in,
                              void* d_out, int out_size, void* d_ws, size_t ws_size,
                              hipStream_t stream) {
    const float* x_c   = (const float*)d_in[0];
    const float* y_c   = (const float*)d_in[1];
    const float* gp    = (const float*)d_in[2];
    const float* sigma = (const float*)d_in[3];
    float* out = (float*)d_out;

    dim3 grid(B_ * 64);      // 512 blocks: 8 batches x 8 my-groups x 8 mx-groups
    dim3 block(BLK);
    rbf_sep<<<grid, block, 0, stream>>>(x_c, y_c, gp, sigma, out);
}